// Round 10
// baseline (354.334 us; speedup 1.0000x reference)
//
#include <hip/hip_runtime.h>

// ---------------------------------------------------------------------------
// AttentionHead: B=4, C=256, N=4096, QK=64. Column-softmax attention.
// R1's measured-best pipeline restored verbatim (attn 57us, proj 17, colsum
// 10.5, transpose 16), with ONE change: mlp1+mlp2 fused through LDS (hdn
// never hits HBM). Everything else untouched -- R4-R9 "improvements" to attn
// all regressed (130-150us vs 57us); see session journal.
// Workspace: 29,884,416 bytes.
// ---------------------------------------------------------------------------

typedef unsigned short u16;
typedef __attribute__((ext_vector_type(8))) unsigned short ushort8;
typedef __attribute__((ext_vector_type(8))) __bf16 bf16x8;
typedef __attribute__((ext_vector_type(4))) float f32x4;

#define MFMA16(a, b, c) __builtin_amdgcn_mfma_f32_16x16x32_bf16((a), (b), (c), 0, 0, 0)

__device__ __forceinline__ u16 f2bf(float f) {
  unsigned int u = __builtin_bit_cast(unsigned int, f);
  u += 0x7FFFu + ((u >> 16) & 1u);  // round-to-nearest-even
  return (u16)(u >> 16);
}

__device__ __forceinline__ bf16x8 ld8(const u16* p) {
  return __builtin_bit_cast(bf16x8, *reinterpret_cast<const ushort8*>(p));
}

__device__ __forceinline__ f32x4 fz4() {
  f32x4 z = {0.f, 0.f, 0.f, 0.f};
  return z;
}

// ---- convert all weight matrices fp32 -> bf16 (one launch) ----------------
__global__ __launch_bounds__(256) void k_convert(
    const float* __restrict__ wq, const float* __restrict__ wk,
    const float* __restrict__ wv, const float* __restrict__ w1,
    const float* __restrict__ w2, u16* __restrict__ dq, u16* __restrict__ dk,
    u16* __restrict__ dv, u16* __restrict__ d1, u16* __restrict__ d2) {
  int i = blockIdx.x * 256 + threadIdx.x;
  if (i < 16384)       dq[i]           = f2bf(wq[i]);
  else if (i < 32768)  dk[i - 16384]   = f2bf(wk[i - 16384]);
  else if (i < 98304)  dv[i - 32768]   = f2bf(wv[i - 32768]);
  else if (i < 163840) d1[i - 98304]   = f2bf(w1[i - 98304]);
  else                 d2[i - 163840]  = f2bf(w2[i - 163840]);
}

// ---- x [b][256][4096] fp32 -> xT [b][4096][256] bf16 (LDS-tiled) ----------
__global__ __launch_bounds__(256) void k_transpose(const float* __restrict__ x,
                                                   u16* __restrict__ xT) {
  __shared__ float t[64][65];
  int n0 = blockIdx.x * 64, c0 = blockIdx.y * 64, b = blockIdx.z;
  int tx = threadIdx.x & 63, ty = threadIdx.x >> 6;
  const float* xb = x + ((size_t)b * 256 + c0) * 4096 + n0;
#pragma unroll
  for (int i = 0; i < 64; i += 4) t[ty + i][tx] = xb[(size_t)(ty + i) * 4096 + tx];
  __syncthreads();
  u16* xo = xT + ((size_t)b * 4096 + n0) * 256 + c0;
#pragma unroll
  for (int i = 0; i < 64; i += 4) xo[(size_t)(ty + i) * 256 + tx] = f2bf(t[tx][ty + i]);
}

// ---- fused QKV projection (R1 verbatim) -----------------------------------
// Q/K (orientation D[pos][o]): A = xT rows, B = W rows -> Qt/Kt[b][pos][64]
// V   (orientation D[o][pos]): A = WV rows, B = xT rows -> Vc[b][256][pos]
__global__ __launch_bounds__(256) void k_proj(
    const u16* __restrict__ xT, const u16* __restrict__ wq,
    const u16* __restrict__ wk, const u16* __restrict__ wv,
    const float* __restrict__ bQ, const float* __restrict__ bK,
    const float* __restrict__ bV, const float* __restrict__ PE,
    u16* __restrict__ Qt, u16* __restrict__ Kt, u16* __restrict__ Vc) {
  int n0 = blockIdx.x * 64, b = blockIdx.y;
  int lane = threadIdx.x & 63, wid = threadIdx.x >> 6;
  int l15 = lane & 15, g = lane >> 4;
  const u16* xrow = xT + ((size_t)b * 4096 + n0) * 256;

  f32x4 aq[4], ak[4], av[4][4];
#pragma unroll
  for (int m = 0; m < 4; ++m) {
    aq[m] = fz4();
    ak[m] = fz4();
#pragma unroll
    for (int n = 0; n < 4; ++n) av[m][n] = fz4();
  }

  for (int kk = 0; kk < 8; ++kk) {
    int ko = kk * 32 + g * 8;
    bf16x8 xa[4];
#pragma unroll
    for (int m = 0; m < 4; ++m) xa[m] = ld8(xrow + (16 * m + l15) * 256 + ko);
    bf16x8 fq = ld8(wq + (16 * wid + l15) * 256 + ko);
    bf16x8 fk = ld8(wk + (16 * wid + l15) * 256 + ko);
#pragma unroll
    for (int m = 0; m < 4; ++m) {
      aq[m] = MFMA16(xa[m], fq, aq[m]);
      ak[m] = MFMA16(xa[m], fk, ak[m]);
    }
    bf16x8 fv[4];
#pragma unroll
    for (int m = 0; m < 4; ++m) fv[m] = ld8(wv + (64 * wid + 16 * m + l15) * 256 + ko);
#pragma unroll
    for (int m = 0; m < 4; ++m)
#pragma unroll
      for (int n = 0; n < 4; ++n) av[m][n] = MFMA16(fv[m], xa[n], av[m][n]);
  }

  // Q/K epilogue: + bias + PE, store [pos][d]
  int o = 16 * wid + l15;
#pragma unroll
  for (int m = 0; m < 4; ++m)
#pragma unroll
    for (int r = 0; r < 4; ++r) {
      int pos = n0 + 16 * m + 4 * g + r;
      float pe = PE[o * 4096 + pos];
      Qt[((size_t)b * 4096 + pos) * 64 + o] = f2bf(aq[m][r] + bQ[o] + pe);
      Kt[((size_t)b * 4096 + pos) * 64 + o] = f2bf(ak[m][r] + bK[o] + pe);
    }
  // V epilogue: + bias, store [c][pos]
#pragma unroll
  for (int m = 0; m < 4; ++m) {
    int ov = 64 * wid + 16 * m + 4 * g;
#pragma unroll
    for (int r = 0; r < 4; ++r) {
      float bvv = bV[ov + r];
#pragma unroll
      for (int n = 0; n < 4; ++n) {
        int pos = n0 + 16 * n + l15;
        Vc[((size_t)b * 256 + ov + r) * 4096 + pos] = f2bf(av[m][n][r] + bvv);
      }
    }
  }
}

// ---- pass 1: column sums of exp(S/8) -> reciprocal (R1 verbatim) ----------
__global__ __launch_bounds__(256) void k_colsum(const u16* __restrict__ Qt,
                                                const u16* __restrict__ Kt,
                                                float* __restrict__ rs) {
  int j0 = blockIdx.x * 64, b = blockIdx.y;
  int lane = threadIdx.x & 63, wid = threadIdx.x >> 6;
  int l15 = lane & 15, g = lane >> 4;
  const u16* qb = Qt + (size_t)b * 262144;
  const u16* kb = Kt + (size_t)b * 262144;
  int j = j0 + 16 * wid + l15;
  bf16x8 fk[2];
#pragma unroll
  for (int h = 0; h < 2; ++h) fk[h] = ld8(kb + j * 64 + h * 32 + 8 * g);
  float part = 0.f;
  for (int i0 = 0; i0 < 4096; i0 += 64) {
    f32x4 acc[4];
#pragma unroll
    for (int m = 0; m < 4; ++m) acc[m] = fz4();
#pragma unroll
    for (int m = 0; m < 4; ++m) {
      const u16* qr = qb + (i0 + 16 * m + l15) * 64;
      acc[m] = MFMA16(ld8(qr + 8 * g), fk[0], acc[m]);
      acc[m] = MFMA16(ld8(qr + 32 + 8 * g), fk[1], acc[m]);
    }
#pragma unroll
    for (int m = 0; m < 4; ++m)
#pragma unroll
      for (int r = 0; r < 4; ++r) part += __expf(acc[m][r] * 0.125f);
  }
  part += __shfl_xor(part, 16);
  part += __shfl_xor(part, 32);
  if (g == 0) rs[b * 4096 + j] = 1.0f / part;
}

// ---- pass 2: O = (exp(S/8)*rs_j) @ V, P via LDS (R1 verbatim) -------------
__global__ __launch_bounds__(256) void k_attn(
    const u16* __restrict__ Qt, const u16* __restrict__ Kt,
    const u16* __restrict__ Vc, const float* __restrict__ rs,
    u16* __restrict__ attT) {
  __shared__ u16 P[64][72];  // pitch 72 (16B-aligned rows, spreads banks)
  int i0 = blockIdx.x * 64, b = blockIdx.y;
  int lane = threadIdx.x & 63, wid = threadIdx.x >> 6;
  int l15 = lane & 15, g = lane >> 4;
  const u16* qb = Qt + (size_t)b * 262144;
  const u16* kb = Kt + (size_t)b * 262144;
  const u16* vb = Vc + (size_t)b * 1048576;
  const float* rsb = rs + b * 4096;

  bf16x8 aq[4][2];  // this block's Q rows, held in registers for all j
#pragma unroll
  for (int m = 0; m < 4; ++m)
#pragma unroll
    for (int h = 0; h < 2; ++h)
      aq[m][h] = ld8(qb + (i0 + 16 * m + l15) * 64 + h * 32 + 8 * g);

  f32x4 oacc[4][4];
#pragma unroll
  for (int m = 0; m < 4; ++m)
#pragma unroll
    for (int n = 0; n < 4; ++n) oacc[m][n] = fz4();

  for (int j0 = 0; j0 < 4096; j0 += 64) {
    const u16* kr = kb + (j0 + 16 * wid + l15) * 64;
    bf16x8 fk0 = ld8(kr + 8 * g);
    bf16x8 fk1 = ld8(kr + 32 + 8 * g);
    float rsc = rsb[j0 + 16 * wid + l15];
    f32x4 s[4];
#pragma unroll
    for (int m = 0; m < 4; ++m) {
      s[m] = fz4();
      s[m] = MFMA16(aq[m][0], fk0, s[m]);
      s[m] = MFMA16(aq[m][1], fk1, s[m]);
    }
#pragma unroll
    for (int m = 0; m < 4; ++m)
#pragma unroll
      for (int r = 0; r < 4; ++r)
        P[16 * m + 4 * g + r][16 * wid + l15] = f2bf(__expf(s[m][r] * 0.125f) * rsc);
    __syncthreads();
#pragma unroll
    for (int h = 0; h < 2; ++h) {
      bf16x8 ap[4];
#pragma unroll
      for (int m = 0; m < 4; ++m) ap[m] = ld8(&P[16 * m + l15][h * 32 + 8 * g]);
#pragma unroll
      for (int n = 0; n < 4; ++n) {
        bf16x8 fv = ld8(vb + (size_t)(64 * wid + 16 * n + l15) * 4096 + j0 + h * 32 + 8 * g);
#pragma unroll
        for (int m = 0; m < 4; ++m) oacc[m][n] = MFMA16(ap[m], fv, oacc[m][n]);
      }
    }
    __syncthreads();
  }
#pragma unroll
  for (int m = 0; m < 4; ++m)
#pragma unroll
    for (int n = 0; n < 4; ++n) {
      int c = 64 * wid + 16 * n + l15;
#pragma unroll
      for (int r = 0; r < 4; ++r) {
        int pos = i0 + 16 * m + 4 * g + r;
        attT[((size_t)b * 4096 + pos) * 256 + c] = f2bf(oacc[m][n][r]);
      }
    }
}

// ---- fused MLP: R1's mlp1 and mlp2 bodies joined through LDS --------------
// Grid (64,4), 64-pos tiles (same shapes R1 measured). hdn never hits HBM.
__global__ __launch_bounds__(256) void k_mlp(
    const u16* __restrict__ attT, const u16* __restrict__ w1,
    const float* __restrict__ b1, const u16* __restrict__ w2,
    const float* __restrict__ b2, const float* __restrict__ x,
    float* __restrict__ out) {
  __shared__ u16 hdnS[64][264];
  int n0 = blockIdx.x * 64, b = blockIdx.y;
  int lane = threadIdx.x & 63, wid = threadIdx.x >> 6;
  int l15 = lane & 15, g = lane >> 4;
  const u16* arow = attT + ((size_t)b * 4096 + n0) * 256;

  // stage 1 (R1 mlp1): hdn = mish(att @ W1^T + b1) -> LDS
  {
    f32x4 acc[4][4];
#pragma unroll
    for (int m = 0; m < 4; ++m)
#pragma unroll
      for (int n = 0; n < 4; ++n) acc[m][n] = fz4();
    for (int kk = 0; kk < 8; ++kk) {
      int ko = kk * 32 + 8 * g;
      bf16x8 am[4], bn[4];
#pragma unroll
      for (int m = 0; m < 4; ++m) am[m] = ld8(arow + (16 * m + l15) * 256 + ko);
#pragma unroll
      for (int n = 0; n < 4; ++n) bn[n] = ld8(w1 + (64 * wid + 16 * n + l15) * 256 + ko);
#pragma unroll
      for (int m = 0; m < 4; ++m)
#pragma unroll
        for (int n = 0; n < 4; ++n) acc[m][n] = MFMA16(am[m], bn[n], acc[m][n]);
    }
#pragma unroll
    for (int m = 0; m < 4; ++m)
#pragma unroll
      for (int n = 0; n < 4; ++n) {
        int hh = 64 * wid + 16 * n + l15;
        float bb = b1[hh];
#pragma unroll
        for (int r = 0; r < 4; ++r) {
          float v = acc[m][n][r] + bb;
          float sp = (v > 15.f) ? v : __logf(1.f + __expf(v));
          float e2 = __expf(-2.f * sp);
          float th = (1.f - e2) / (1.f + e2);
          hdnS[16 * m + 4 * g + r][hh] = f2bf(v * th);
        }
      }
  }
  __syncthreads();

  // stage 2 (R1 mlp2): out = hdn @ W2^T + b2 + x
  {
    f32x4 acc[4][4];
#pragma unroll
    for (int m = 0; m < 4; ++m)
#pragma unroll
      for (int n = 0; n < 4; ++n) acc[m][n] = fz4();
    for (int kk = 0; kk < 8; ++kk) {
      int ko = kk * 32 + 8 * g;
      bf16x8 am[4], bn[4];
#pragma unroll
      for (int m = 0; m < 4; ++m) am[m] = ld8(w2 + (64 * wid + 16 * m + l15) * 256 + ko);
#pragma unroll
      for (int n = 0; n < 4; ++n) bn[n] = ld8(&hdnS[16 * n + l15][ko]);
#pragma unroll
      for (int m = 0; m < 4; ++m)
#pragma unroll
        for (int n = 0; n < 4; ++n) acc[m][n] = MFMA16(am[m], bn[n], acc[m][n]);
    }
#pragma unroll
    for (int m = 0; m < 4; ++m)
#pragma unroll
      for (int r = 0; r < 4; ++r) {
        int o = 64 * wid + 16 * m + 4 * g + r;
        float bias = b2[o];
#pragma unroll
        for (int n = 0; n < 4; ++n) {
          int pos = n0 + 16 * n + l15;
          size_t idx = ((size_t)b * 256 + o) * 4096 + pos;
          out[idx] = acc[m][n][r] + bias + x[idx];
        }
      }
  }
}

// ---- workspace layout (bytes) ---------------------------------------------
#define WS_XT 0u          //  8,388,608  xT  [4][4096][256] bf16
#define WS_QT 8388608u    //  2,097,152  Qt  [4][4096][64]  bf16
#define WS_KT 10485760u   //  2,097,152  Kt  [4][4096][64]  bf16
#define WS_VC 12582912u   //  8,388,608  Vc  [4][256][4096] bf16
#define WS_ATT 20971520u  //  8,388,608  attT[4][4096][256] bf16
#define WS_RS 29360128u   //     65,536  rs  [4][4096]      fp32
#define WS_WQ 29425664u   //     32,768
#define WS_WK 29458432u   //     32,768
#define WS_WV 29491200u   //    131,072
#define WS_W1 29622272u   //    131,072
#define WS_W2 29753344u   //    131,072   (end: 29,884,416)

extern "C" void kernel_launch(void* const* d_in, const int* in_sizes, int n_in,
                              void* d_out, int out_size, void* d_ws, size_t ws_size,
                              hipStream_t stream) {
  (void)in_sizes; (void)n_in; (void)out_size; (void)ws_size;
  const float* x  = (const float*)d_in[0];
  const float* WQ = (const float*)d_in[1];
  const float* bQ = (const float*)d_in[2];
  const float* WK = (const float*)d_in[3];
  const float* bK = (const float*)d_in[4];
  const float* WV = (const float*)d_in[5];
  const float* bV = (const float*)d_in[6];
  const float* PE = (const float*)d_in[7];
  const float* W1 = (const float*)d_in[8];
  const float* b1 = (const float*)d_in[9];
  const float* W2 = (const float*)d_in[10];
  const float* b2 = (const float*)d_in[11];
  float* out = (float*)d_out;
  char* ws = (char*)d_ws;

  u16* xT   = (u16*)(ws + WS_XT);
  u16* Qt   = (u16*)(ws + WS_QT);
  u16* Kt   = (u16*)(ws + WS_KT);
  u16* Vc   = (u16*)(ws + WS_VC);
  u16* attT = (u16*)(ws + WS_ATT);
  float* rs = (float*)(ws + WS_RS);
  u16* wqB  = (u16*)(ws + WS_WQ);
  u16* wkB  = (u16*)(ws + WS_WK);
  u16* wvB  = (u16*)(ws + WS_WV);
  u16* w1B  = (u16*)(ws + WS_W1);
  u16* w2B  = (u16*)(ws + WS_W2);

  k_convert<<<896, 256, 0, stream>>>(WQ, WK, WV, W1, W2, wqB, wkB, wvB, w1B, w2B);
  k_transpose<<<dim3(64, 4, 4), 256, 0, stream>>>(x, xT);
  k_proj<<<dim3(64, 4), 256, 0, stream>>>(xT, wqB, wkB, wvB, bQ, bK, bV, PE, Qt, Kt, Vc);
  k_colsum<<<dim3(64, 4), 256, 0, stream>>>(Qt, Kt, rs);
  k_attn<<<dim3(64, 4), 256, 0, stream>>>(Qt, Kt, Vc, rs, attT);
  k_mlp<<<dim3(64, 4), 256, 0, stream>>>(attT, w1B, b1, w2B, b2, x, out);
}

// Round 11
// 305.260 us; speedup vs baseline: 1.1608x; 1.1608x over previous
//
#include <hip/hip_runtime.h>

// ---------------------------------------------------------------------------
// AttentionHead: B=4, C=256, N=4096, QK=64. Column-softmax attention.
// R10 pipeline with ONE change: k_attn uses 512-thread blocks (8 waves,
// 2 waves/SIMD) and 128-j steps -- 2x latency hiding, half the barriers,
// identical math/work. (R10 post-mortem: R1's 57us attn is unreachable --
// bench env changed after R2; identical code now runs 156us with 10x FETCH.)
// Workspace: 29,884,416 bytes.
// ---------------------------------------------------------------------------

typedef unsigned short u16;
typedef __attribute__((ext_vector_type(8))) unsigned short ushort8;
typedef __attribute__((ext_vector_type(8))) __bf16 bf16x8;
typedef __attribute__((ext_vector_type(4))) float f32x4;

#define MFMA16(a, b, c) __builtin_amdgcn_mfma_f32_16x16x32_bf16((a), (b), (c), 0, 0, 0)

__device__ __forceinline__ u16 f2bf(float f) {
  unsigned int u = __builtin_bit_cast(unsigned int, f);
  u += 0x7FFFu + ((u >> 16) & 1u);  // round-to-nearest-even
  return (u16)(u >> 16);
}

__device__ __forceinline__ bf16x8 ld8(const u16* p) {
  return __builtin_bit_cast(bf16x8, *reinterpret_cast<const ushort8*>(p));
}

__device__ __forceinline__ f32x4 fz4() {
  f32x4 z = {0.f, 0.f, 0.f, 0.f};
  return z;
}

// ---- convert all weight matrices fp32 -> bf16 (one launch) ----------------
__global__ __launch_bounds__(256) void k_convert(
    const float* __restrict__ wq, const float* __restrict__ wk,
    const float* __restrict__ wv, const float* __restrict__ w1,
    const float* __restrict__ w2, u16* __restrict__ dq, u16* __restrict__ dk,
    u16* __restrict__ dv, u16* __restrict__ d1, u16* __restrict__ d2) {
  int i = blockIdx.x * 256 + threadIdx.x;
  if (i < 16384)       dq[i]           = f2bf(wq[i]);
  else if (i < 32768)  dk[i - 16384]   = f2bf(wk[i - 16384]);
  else if (i < 98304)  dv[i - 32768]   = f2bf(wv[i - 32768]);
  else if (i < 163840) d1[i - 98304]   = f2bf(w1[i - 98304]);
  else                 d2[i - 163840]  = f2bf(w2[i - 163840]);
}

// ---- x [b][256][4096] fp32 -> xT [b][4096][256] bf16 (LDS-tiled) ----------
__global__ __launch_bounds__(256) void k_transpose(const float* __restrict__ x,
                                                   u16* __restrict__ xT) {
  __shared__ float t[64][65];
  int n0 = blockIdx.x * 64, c0 = blockIdx.y * 64, b = blockIdx.z;
  int tx = threadIdx.x & 63, ty = threadIdx.x >> 6;
  const float* xb = x + ((size_t)b * 256 + c0) * 4096 + n0;
#pragma unroll
  for (int i = 0; i < 64; i += 4) t[ty + i][tx] = xb[(size_t)(ty + i) * 4096 + tx];
  __syncthreads();
  u16* xo = xT + ((size_t)b * 4096 + n0) * 256 + c0;
#pragma unroll
  for (int i = 0; i < 64; i += 4) xo[(size_t)(ty + i) * 256 + tx] = f2bf(t[tx][ty + i]);
}

// ---- fused QKV projection (R1 verbatim) -----------------------------------
__global__ __launch_bounds__(256) void k_proj(
    const u16* __restrict__ xT, const u16* __restrict__ wq,
    const u16* __restrict__ wk, const u16* __restrict__ wv,
    const float* __restrict__ bQ, const float* __restrict__ bK,
    const float* __restrict__ bV, const float* __restrict__ PE,
    u16* __restrict__ Qt, u16* __restrict__ Kt, u16* __restrict__ Vc) {
  int n0 = blockIdx.x * 64, b = blockIdx.y;
  int lane = threadIdx.x & 63, wid = threadIdx.x >> 6;
  int l15 = lane & 15, g = lane >> 4;
  const u16* xrow = xT + ((size_t)b * 4096 + n0) * 256;

  f32x4 aq[4], ak[4], av[4][4];
#pragma unroll
  for (int m = 0; m < 4; ++m) {
    aq[m] = fz4();
    ak[m] = fz4();
#pragma unroll
    for (int n = 0; n < 4; ++n) av[m][n] = fz4();
  }

  for (int kk = 0; kk < 8; ++kk) {
    int ko = kk * 32 + g * 8;
    bf16x8 xa[4];
#pragma unroll
    for (int m = 0; m < 4; ++m) xa[m] = ld8(xrow + (16 * m + l15) * 256 + ko);
    bf16x8 fq = ld8(wq + (16 * wid + l15) * 256 + ko);
    bf16x8 fk = ld8(wk + (16 * wid + l15) * 256 + ko);
#pragma unroll
    for (int m = 0; m < 4; ++m) {
      aq[m] = MFMA16(xa[m], fq, aq[m]);
      ak[m] = MFMA16(xa[m], fk, ak[m]);
    }
    bf16x8 fv[4];
#pragma unroll
    for (int m = 0; m < 4; ++m) fv[m] = ld8(wv + (64 * wid + 16 * m + l15) * 256 + ko);
#pragma unroll
    for (int m = 0; m < 4; ++m)
#pragma unroll
      for (int n = 0; n < 4; ++n) av[m][n] = MFMA16(fv[m], xa[n], av[m][n]);
  }

  int o = 16 * wid + l15;
#pragma unroll
  for (int m = 0; m < 4; ++m)
#pragma unroll
    for (int r = 0; r < 4; ++r) {
      int pos = n0 + 16 * m + 4 * g + r;
      float pe = PE[o * 4096 + pos];
      Qt[((size_t)b * 4096 + pos) * 64 + o] = f2bf(aq[m][r] + bQ[o] + pe);
      Kt[((size_t)b * 4096 + pos) * 64 + o] = f2bf(ak[m][r] + bK[o] + pe);
    }
#pragma unroll
  for (int m = 0; m < 4; ++m) {
    int ov = 64 * wid + 16 * m + 4 * g;
#pragma unroll
    for (int r = 0; r < 4; ++r) {
      float bvv = bV[ov + r];
#pragma unroll
      for (int n = 0; n < 4; ++n) {
        int pos = n0 + 16 * n + l15;
        Vc[((size_t)b * 256 + ov + r) * 4096 + pos] = f2bf(av[m][n][r] + bvv);
      }
    }
  }
}

// ---- pass 1: column sums of exp(S/8) -> reciprocal (R1 verbatim) ----------
__global__ __launch_bounds__(256) void k_colsum(const u16* __restrict__ Qt,
                                                const u16* __restrict__ Kt,
                                                float* __restrict__ rs) {
  int j0 = blockIdx.x * 64, b = blockIdx.y;
  int lane = threadIdx.x & 63, wid = threadIdx.x >> 6;
  int l15 = lane & 15, g = lane >> 4;
  const u16* qb = Qt + (size_t)b * 262144;
  const u16* kb = Kt + (size_t)b * 262144;
  int j = j0 + 16 * wid + l15;
  bf16x8 fk[2];
#pragma unroll
  for (int h = 0; h < 2; ++h) fk[h] = ld8(kb + j * 64 + h * 32 + 8 * g);
  float part = 0.f;
  for (int i0 = 0; i0 < 4096; i0 += 64) {
    f32x4 acc[4];
#pragma unroll
    for (int m = 0; m < 4; ++m) acc[m] = fz4();
#pragma unroll
    for (int m = 0; m < 4; ++m) {
      const u16* qr = qb + (i0 + 16 * m + l15) * 64;
      acc[m] = MFMA16(ld8(qr + 8 * g), fk[0], acc[m]);
      acc[m] = MFMA16(ld8(qr + 32 + 8 * g), fk[1], acc[m]);
    }
#pragma unroll
    for (int m = 0; m < 4; ++m)
#pragma unroll
      for (int r = 0; r < 4; ++r) part += __expf(acc[m][r] * 0.125f);
  }
  part += __shfl_xor(part, 16);
  part += __shfl_xor(part, 32);
  if (g == 0) rs[b * 4096 + j] = 1.0f / part;
}

// ---- pass 2: O = (exp(S/8)*rs_j) @ V --------------------------------------
// 512-thread blocks (8 waves, 2 waves/SIMD), 128-j steps. Wave w: S+exp for
// j-strip 16w (same per-wave work as R10); PV over channel strip 32w.
// Grid (64,4) = 256 blocks, 1 block/CU, 16 waves/CU equivalent occupancy 2x R10.
__global__ __launch_bounds__(512) void k_attn(
    const u16* __restrict__ Qt, const u16* __restrict__ Kt,
    const u16* __restrict__ Vc, const float* __restrict__ rs,
    u16* __restrict__ attT) {
  __shared__ u16 P[64][136];  // 128 j + pad (row 272 B; same bank profile as R1's 72)
  int i0 = blockIdx.x * 64, b = blockIdx.y;
  int lane = threadIdx.x & 63, wid = threadIdx.x >> 6;  // wid in [0,8)
  int l15 = lane & 15, g = lane >> 4;
  const u16* qb = Qt + (size_t)b * 262144;
  const u16* kb = Kt + (size_t)b * 262144;
  const u16* vb = Vc + (size_t)b * 1048576;
  const float* rsb = rs + b * 4096;

  bf16x8 aq[4][2];  // block's Q rows (i = i0+16m+l15), held for all j
#pragma unroll
  for (int m = 0; m < 4; ++m)
#pragma unroll
    for (int h = 0; h < 2; ++h)
      aq[m][h] = ld8(qb + (i0 + 16 * m + l15) * 64 + h * 32 + 8 * g);

  f32x4 oacc[4][2];  // lane: i = i0+16m+4g+r, c = 32*wid+16n+l15
#pragma unroll
  for (int m = 0; m < 4; ++m)
#pragma unroll
    for (int n = 0; n < 2; ++n) oacc[m][n] = fz4();

  for (int j0 = 0; j0 < 4096; j0 += 128) {
    // S + exp for this wave's 16-j strip (j = j0 + 16*wid + l15)
    const u16* kr = kb + (size_t)(j0 + 16 * wid + l15) * 64;
    bf16x8 fk0 = ld8(kr + 8 * g);
    bf16x8 fk1 = ld8(kr + 32 + 8 * g);
    float rsc = rsb[j0 + 16 * wid + l15];
    f32x4 s[4];
#pragma unroll
    for (int m = 0; m < 4; ++m) {
      s[m] = fz4();
      s[m] = MFMA16(aq[m][0], fk0, s[m]);
      s[m] = MFMA16(aq[m][1], fk1, s[m]);
    }
#pragma unroll
    for (int m = 0; m < 4; ++m)
#pragma unroll
      for (int r = 0; r < 4; ++r)
        P[16 * m + 4 * g + r][16 * wid + l15] = f2bf(__expf(s[m][r] * 0.125f) * rsc);
    __syncthreads();
    // PV: A = P rows i (4 k-chunks of 32 j), B = V rows c (strip 32*wid)
#pragma unroll
    for (int h = 0; h < 4; ++h) {
      bf16x8 ap[4];
#pragma unroll
      for (int m = 0; m < 4; ++m) ap[m] = ld8(&P[16 * m + l15][h * 32 + 8 * g]);
#pragma unroll
      for (int n = 0; n < 2; ++n) {
        bf16x8 fv = ld8(vb + (size_t)(32 * wid + 16 * n + l15) * 4096 + j0 + h * 32 + 8 * g);
#pragma unroll
        for (int m = 0; m < 4; ++m) oacc[m][n] = MFMA16(ap[m], fv, oacc[m][n]);
      }
    }
    __syncthreads();
  }
#pragma unroll
  for (int m = 0; m < 4; ++m)
#pragma unroll
    for (int n = 0; n < 2; ++n) {
      int c = 32 * wid + 16 * n + l15;
#pragma unroll
      for (int r = 0; r < 4; ++r) {
        int pos = i0 + 16 * m + 4 * g + r;
        attT[((size_t)b * 4096 + pos) * 256 + c] = f2bf(oacc[m][n][r]);
      }
    }
}

// ---- fused MLP (R10 verbatim): mish(W1 att+b1) -> LDS -> W2 .. + b2 + x ---
__global__ __launch_bounds__(256) void k_mlp(
    const u16* __restrict__ attT, const u16* __restrict__ w1,
    const float* __restrict__ b1, const u16* __restrict__ w2,
    const float* __restrict__ b2, const float* __restrict__ x,
    float* __restrict__ out) {
  __shared__ u16 hdnS[64][264];
  int n0 = blockIdx.x * 64, b = blockIdx.y;
  int lane = threadIdx.x & 63, wid = threadIdx.x >> 6;
  int l15 = lane & 15, g = lane >> 4;
  const u16* arow = attT + ((size_t)b * 4096 + n0) * 256;

  {
    f32x4 acc[4][4];
#pragma unroll
    for (int m = 0; m < 4; ++m)
#pragma unroll
      for (int n = 0; n < 4; ++n) acc[m][n] = fz4();
    for (int kk = 0; kk < 8; ++kk) {
      int ko = kk * 32 + 8 * g;
      bf16x8 am[4], bn[4];
#pragma unroll
      for (int m = 0; m < 4; ++m) am[m] = ld8(arow + (16 * m + l15) * 256 + ko);
#pragma unroll
      for (int n = 0; n < 4; ++n) bn[n] = ld8(w1 + (64 * wid + 16 * n + l15) * 256 + ko);
#pragma unroll
      for (int m = 0; m < 4; ++m)
#pragma unroll
        for (int n = 0; n < 4; ++n) acc[m][n] = MFMA16(am[m], bn[n], acc[m][n]);
    }
#pragma unroll
    for (int m = 0; m < 4; ++m)
#pragma unroll
      for (int n = 0; n < 4; ++n) {
        int hh = 64 * wid + 16 * n + l15;
        float bb = b1[hh];
#pragma unroll
        for (int r = 0; r < 4; ++r) {
          float v = acc[m][n][r] + bb;
          float sp = (v > 15.f) ? v : __logf(1.f + __expf(v));
          float e2 = __expf(-2.f * sp);
          float th = (1.f - e2) / (1.f + e2);
          hdnS[16 * m + 4 * g + r][hh] = f2bf(v * th);
        }
      }
  }
  __syncthreads();

  {
    f32x4 acc[4][4];
#pragma unroll
    for (int m = 0; m < 4; ++m)
#pragma unroll
      for (int n = 0; n < 4; ++n) acc[m][n] = fz4();
    for (int kk = 0; kk < 8; ++kk) {
      int ko = kk * 32 + 8 * g;
      bf16x8 am[4], bn[4];
#pragma unroll
      for (int m = 0; m < 4; ++m) am[m] = ld8(w2 + (64 * wid + 16 * m + l15) * 256 + ko);
#pragma unroll
      for (int n = 0; n < 4; ++n) bn[n] = ld8(&hdnS[16 * n + l15][ko]);
#pragma unroll
      for (int m = 0; m < 4; ++m)
#pragma unroll
        for (int n = 0; n < 4; ++n) acc[m][n] = MFMA16(am[m], bn[n], acc[m][n]);
    }
#pragma unroll
    for (int m = 0; m < 4; ++m)
#pragma unroll
      for (int r = 0; r < 4; ++r) {
        int o = 64 * wid + 16 * m + 4 * g + r;
        float bias = b2[o];
#pragma unroll
        for (int n = 0; n < 4; ++n) {
          int pos = n0 + 16 * n + l15;
          size_t idx = ((size_t)b * 256 + o) * 4096 + pos;
          out[idx] = acc[m][n][r] + bias + x[idx];
        }
      }
  }
}

// ---- workspace layout (bytes) ---------------------------------------------
#define WS_XT 0u          //  8,388,608  xT  [4][4096][256] bf16
#define WS_QT 8388608u    //  2,097,152  Qt  [4][4096][64]  bf16
#define WS_KT 10485760u   //  2,097,152  Kt  [4][4096][64]  bf16
#define WS_VC 12582912u   //  8,388,608  Vc  [4][256][4096] bf16
#define WS_ATT 20971520u  //  8,388,608  attT[4][4096][256] bf16
#define WS_RS 29360128u   //     65,536  rs  [4][4096]      fp32
#define WS_WQ 29425664u   //     32,768
#define WS_WK 29458432u   //     32,768
#define WS_WV 29491200u   //    131,072
#define WS_W1 29622272u   //    131,072
#define WS_W2 29753344u   //    131,072   (end: 29,884,416)

extern "C" void kernel_launch(void* const* d_in, const int* in_sizes, int n_in,
                              void* d_out, int out_size, void* d_ws, size_t ws_size,
                              hipStream_t stream) {
  (void)in_sizes; (void)n_in; (void)out_size; (void)ws_size;
  const float* x  = (const float*)d_in[0];
  const float* WQ = (const float*)d_in[1];
  const float* bQ = (const float*)d_in[2];
  const float* WK = (const float*)d_in[3];
  const float* bK = (const float*)d_in[4];
  const float* WV = (const float*)d_in[5];
  const float* bV = (const float*)d_in[6];
  const float* PE = (const float*)d_in[7];
  const float* W1 = (const float*)d_in[8];
  const float* b1 = (const float*)d_in[9];
  const float* W2 = (const float*)d_in[10];
  const float* b2 = (const float*)d_in[11];
  float* out = (float*)d_out;
  char* ws = (char*)d_ws;

  u16* xT   = (u16*)(ws + WS_XT);
  u16* Qt   = (u16*)(ws + WS_QT);
  u16* Kt   = (u16*)(ws + WS_KT);
  u16* Vc   = (u16*)(ws + WS_VC);
  u16* attT = (u16*)(ws + WS_ATT);
  float* rs = (float*)(ws + WS_RS);
  u16* wqB  = (u16*)(ws + WS_WQ);
  u16* wkB  = (u16*)(ws + WS_WK);
  u16* wvB  = (u16*)(ws + WS_WV);
  u16* w1B  = (u16*)(ws + WS_W1);
  u16* w2B  = (u16*)(ws + WS_W2);

  k_convert<<<896, 256, 0, stream>>>(WQ, WK, WV, W1, W2, wqB, wkB, wvB, w1B, w2B);
  k_transpose<<<dim3(64, 4, 4), 256, 0, stream>>>(x, xT);
  k_proj<<<dim3(64, 4), 256, 0, stream>>>(xT, wqB, wkB, wvB, bQ, bK, bV, PE, Qt, Kt, Vc);
  k_colsum<<<dim3(64, 4), 256, 0, stream>>>(Qt, Kt, rs);
  k_attn<<<dim3(64, 4), 512, 0, stream>>>(Qt, Kt, Vc, rs, attT);
  k_mlp<<<dim3(64, 4), 256, 0, stream>>>(attT, w1B, b1, w2B, b2, x, out);
}

// Round 12
// 285.969 us; speedup vs baseline: 1.2391x; 1.0675x over previous
//
#include <hip/hip_runtime.h>

// ---------------------------------------------------------------------------
// AttentionHead: B=4, C=256, N=4096, QK=64. Column-softmax attention.
// R11 + occupancy scaling everywhere (work constant): attn 1024 thr (4
// waves/SIMD, 256-j steps), proj 32-pos tiles grid 512 (2 blk/CU), colsum
// 512 thr (split-i in block), mlp 512 thr (strip-split waves).
// Workspace: 29,884,416 bytes.
// ---------------------------------------------------------------------------

typedef unsigned short u16;
typedef __attribute__((ext_vector_type(8))) unsigned short ushort8;
typedef __attribute__((ext_vector_type(8))) __bf16 bf16x8;
typedef __attribute__((ext_vector_type(4))) float f32x4;

#define MFMA16(a, b, c) __builtin_amdgcn_mfma_f32_16x16x32_bf16((a), (b), (c), 0, 0, 0)

__device__ __forceinline__ u16 f2bf(float f) {
  unsigned int u = __builtin_bit_cast(unsigned int, f);
  u += 0x7FFFu + ((u >> 16) & 1u);  // round-to-nearest-even
  return (u16)(u >> 16);
}

__device__ __forceinline__ bf16x8 ld8(const u16* p) {
  return __builtin_bit_cast(bf16x8, *reinterpret_cast<const ushort8*>(p));
}

__device__ __forceinline__ f32x4 fz4() {
  f32x4 z = {0.f, 0.f, 0.f, 0.f};
  return z;
}

// ---- convert all weight matrices fp32 -> bf16 (one launch) ----------------
__global__ __launch_bounds__(256) void k_convert(
    const float* __restrict__ wq, const float* __restrict__ wk,
    const float* __restrict__ wv, const float* __restrict__ w1,
    const float* __restrict__ w2, u16* __restrict__ dq, u16* __restrict__ dk,
    u16* __restrict__ dv, u16* __restrict__ d1, u16* __restrict__ d2) {
  int i = blockIdx.x * 256 + threadIdx.x;
  if (i < 16384)       dq[i]           = f2bf(wq[i]);
  else if (i < 32768)  dk[i - 16384]   = f2bf(wk[i - 16384]);
  else if (i < 98304)  dv[i - 32768]   = f2bf(wv[i - 32768]);
  else if (i < 163840) d1[i - 98304]   = f2bf(w1[i - 98304]);
  else                 d2[i - 163840]  = f2bf(w2[i - 163840]);
}

// ---- x [b][256][4096] fp32 -> xT [b][4096][256] bf16 (LDS-tiled) ----------
__global__ __launch_bounds__(256) void k_transpose(const float* __restrict__ x,
                                                   u16* __restrict__ xT) {
  __shared__ float t[64][65];
  int n0 = blockIdx.x * 64, c0 = blockIdx.y * 64, b = blockIdx.z;
  int tx = threadIdx.x & 63, ty = threadIdx.x >> 6;
  const float* xb = x + ((size_t)b * 256 + c0) * 4096 + n0;
#pragma unroll
  for (int i = 0; i < 64; i += 4) t[ty + i][tx] = xb[(size_t)(ty + i) * 4096 + tx];
  __syncthreads();
  u16* xo = xT + ((size_t)b * 4096 + n0) * 256 + c0;
#pragma unroll
  for (int i = 0; i < 64; i += 4) xo[(size_t)(ty + i) * 256 + tx] = f2bf(t[tx][ty + i]);
}

// ---- fused QKV projection: 32-pos tiles, grid (128,4) = 2 blocks/CU -------
__global__ __launch_bounds__(256) void k_proj(
    const u16* __restrict__ xT, const u16* __restrict__ wq,
    const u16* __restrict__ wk, const u16* __restrict__ wv,
    const float* __restrict__ bQ, const float* __restrict__ bK,
    const float* __restrict__ bV, const float* __restrict__ PE,
    u16* __restrict__ Qt, u16* __restrict__ Kt, u16* __restrict__ Vc) {
  int n0 = blockIdx.x * 32, b = blockIdx.y;
  int lane = threadIdx.x & 63, wid = threadIdx.x >> 6;
  int l15 = lane & 15, g = lane >> 4;
  const u16* xrow = xT + ((size_t)b * 4096 + n0) * 256;

  f32x4 aq[2], ak[2], av[4][2];
#pragma unroll
  for (int m = 0; m < 2; ++m) { aq[m] = fz4(); ak[m] = fz4(); }
#pragma unroll
  for (int m = 0; m < 4; ++m)
#pragma unroll
    for (int n = 0; n < 2; ++n) av[m][n] = fz4();

  for (int kk = 0; kk < 8; ++kk) {
    int ko = kk * 32 + g * 8;
    bf16x8 xa[2];
#pragma unroll
    for (int m = 0; m < 2; ++m) xa[m] = ld8(xrow + (16 * m + l15) * 256 + ko);
    bf16x8 fq = ld8(wq + (16 * wid + l15) * 256 + ko);
    bf16x8 fk = ld8(wk + (16 * wid + l15) * 256 + ko);
#pragma unroll
    for (int m = 0; m < 2; ++m) {
      aq[m] = MFMA16(xa[m], fq, aq[m]);
      ak[m] = MFMA16(xa[m], fk, ak[m]);
    }
    bf16x8 fv[4];
#pragma unroll
    for (int m = 0; m < 4; ++m) fv[m] = ld8(wv + (64 * wid + 16 * m + l15) * 256 + ko);
#pragma unroll
    for (int m = 0; m < 4; ++m)
#pragma unroll
      for (int n = 0; n < 2; ++n) av[m][n] = MFMA16(fv[m], xa[n], av[m][n]);
  }

  int o = 16 * wid + l15;
#pragma unroll
  for (int m = 0; m < 2; ++m)
#pragma unroll
    for (int r = 0; r < 4; ++r) {
      int pos = n0 + 16 * m + 4 * g + r;
      float pe = PE[o * 4096 + pos];
      Qt[((size_t)b * 4096 + pos) * 64 + o] = f2bf(aq[m][r] + bQ[o] + pe);
      Kt[((size_t)b * 4096 + pos) * 64 + o] = f2bf(ak[m][r] + bK[o] + pe);
    }
#pragma unroll
  for (int m = 0; m < 4; ++m) {
    int ov = 64 * wid + 16 * m + 4 * g;
#pragma unroll
    for (int r = 0; r < 4; ++r) {
      float bvv = bV[ov + r];
#pragma unroll
      for (int n = 0; n < 2; ++n) {
        int pos = n0 + 16 * n + l15;
        Vc[((size_t)b * 256 + ov + r) * 4096 + pos] = f2bf(av[m][n][r] + bvv);
      }
    }
  }
}

// ---- pass 1: column sums, 512 thr: waves 0-3 / 4-7 split the i-range ------
__global__ __launch_bounds__(512) void k_colsum(const u16* __restrict__ Qt,
                                                const u16* __restrict__ Kt,
                                                float* __restrict__ rs) {
  __shared__ float ps[8][16];
  int j0 = blockIdx.x * 64, b = blockIdx.y;
  int lane = threadIdx.x & 63, wid = threadIdx.x >> 6;  // wid in [0,8)
  int l15 = lane & 15, g = lane >> 4;
  int w4 = wid & 3, ihalf = wid >> 2;
  const u16* qb = Qt + (size_t)b * 262144;
  const u16* kb = Kt + (size_t)b * 262144;
  int j = j0 + 16 * w4 + l15;
  bf16x8 fk[2];
#pragma unroll
  for (int h = 0; h < 2; ++h) fk[h] = ld8(kb + j * 64 + h * 32 + 8 * g);
  float part = 0.f;
  for (int i0 = ihalf * 2048; i0 < ihalf * 2048 + 2048; i0 += 64) {
    f32x4 acc[4];
#pragma unroll
    for (int m = 0; m < 4; ++m) acc[m] = fz4();
#pragma unroll
    for (int m = 0; m < 4; ++m) {
      const u16* qr = qb + (i0 + 16 * m + l15) * 64;
      acc[m] = MFMA16(ld8(qr + 8 * g), fk[0], acc[m]);
      acc[m] = MFMA16(ld8(qr + 32 + 8 * g), fk[1], acc[m]);
    }
#pragma unroll
    for (int m = 0; m < 4; ++m)
#pragma unroll
      for (int r = 0; r < 4; ++r) part += __expf(acc[m][r] * 0.125f);
  }
  part += __shfl_xor(part, 16);
  part += __shfl_xor(part, 32);
  if (g == 0) ps[wid][l15] = part;
  __syncthreads();
  if (ihalf == 0 && g == 0)
    rs[b * 4096 + j] = 1.0f / (ps[w4][l15] + ps[w4 + 4][l15]);
}

// ---- pass 2: O = (exp(S/8)*rs_j) @ V, 1024 thr (16 waves, 4/SIMD) ---------
// 256-j steps. Wave w: S+exp for j-strip 16w; PV over channel strip 16w.
__global__ __launch_bounds__(1024) void k_attn(
    const u16* __restrict__ Qt, const u16* __restrict__ Kt,
    const u16* __restrict__ Vc, const float* __restrict__ rs,
    u16* __restrict__ attT) {
  __shared__ u16 P[64][264];  // 256 j + pad (row 528 B, 33x16B)
  int i0 = blockIdx.x * 64, b = blockIdx.y;
  int lane = threadIdx.x & 63, wid = threadIdx.x >> 6;  // wid in [0,16)
  int l15 = lane & 15, g = lane >> 4;
  const u16* qb = Qt + (size_t)b * 262144;
  const u16* kb = Kt + (size_t)b * 262144;
  const u16* vb = Vc + (size_t)b * 1048576;
  const float* rsb = rs + b * 4096;

  bf16x8 aq[4][2];  // block's Q rows (i = i0+16m+l15), held for all j
#pragma unroll
  for (int m = 0; m < 4; ++m)
#pragma unroll
    for (int h = 0; h < 2; ++h)
      aq[m][h] = ld8(qb + (i0 + 16 * m + l15) * 64 + h * 32 + 8 * g);

  f32x4 oacc[4];  // lane: i = i0+16m+4g+r, c = 16*wid+l15
#pragma unroll
  for (int m = 0; m < 4; ++m) oacc[m] = fz4();

  for (int j0 = 0; j0 < 4096; j0 += 256) {
    // S + exp for this wave's 16-j strip (j = j0 + 16*wid + l15)
    const u16* kr = kb + (size_t)(j0 + 16 * wid + l15) * 64;
    bf16x8 fk0 = ld8(kr + 8 * g);
    bf16x8 fk1 = ld8(kr + 32 + 8 * g);
    float rsc = rsb[j0 + 16 * wid + l15];
    f32x4 s[4];
#pragma unroll
    for (int m = 0; m < 4; ++m) {
      s[m] = fz4();
      s[m] = MFMA16(aq[m][0], fk0, s[m]);
      s[m] = MFMA16(aq[m][1], fk1, s[m]);
    }
#pragma unroll
    for (int m = 0; m < 4; ++m)
#pragma unroll
      for (int r = 0; r < 4; ++r)
        P[16 * m + 4 * g + r][16 * wid + l15] = f2bf(__expf(s[m][r] * 0.125f) * rsc);
    __syncthreads();
    // PV: A = P rows i (8 k-chunks of 32 j), B = V rows c (strip 16*wid)
#pragma unroll
    for (int h = 0; h < 8; ++h) {
      bf16x8 ap[4];
#pragma unroll
      for (int m = 0; m < 4; ++m) ap[m] = ld8(&P[16 * m + l15][h * 32 + 8 * g]);
      bf16x8 fv = ld8(vb + (size_t)(16 * wid + l15) * 4096 + j0 + h * 32 + 8 * g);
#pragma unroll
      for (int m = 0; m < 4; ++m) oacc[m] = MFMA16(ap[m], fv, oacc[m]);
    }
    __syncthreads();
  }
  int c = 16 * wid + l15;
#pragma unroll
  for (int m = 0; m < 4; ++m)
#pragma unroll
    for (int r = 0; r < 4; ++r) {
      int pos = i0 + 16 * m + 4 * g + r;
      attT[((size_t)b * 4096 + pos) * 256 + c] = f2bf(oacc[m][r]);
    }
}

// ---- fused MLP, 512 thr: 8 waves, each owns a 32-wide strip per stage -----
__global__ __launch_bounds__(512) void k_mlp(
    const u16* __restrict__ attT, const u16* __restrict__ w1,
    const float* __restrict__ b1, const u16* __restrict__ w2,
    const float* __restrict__ b2, const float* __restrict__ x,
    float* __restrict__ out) {
  __shared__ u16 hdnS[64][264];
  int n0 = blockIdx.x * 64, b = blockIdx.y;
  int lane = threadIdx.x & 63, wid = threadIdx.x >> 6;  // wid in [0,8)
  int l15 = lane & 15, g = lane >> 4;
  const u16* arow = attT + ((size_t)b * 4096 + n0) * 256;

  // stage 1: hdn = mish(att @ W1^T + b1) -> LDS; wave strip = 32 h-channels
  {
    f32x4 acc[4][2];
#pragma unroll
    for (int m = 0; m < 4; ++m)
#pragma unroll
      for (int n = 0; n < 2; ++n) acc[m][n] = fz4();
    for (int kk = 0; kk < 8; ++kk) {
      int ko = kk * 32 + 8 * g;
      bf16x8 am[4], bn[2];
#pragma unroll
      for (int m = 0; m < 4; ++m) am[m] = ld8(arow + (16 * m + l15) * 256 + ko);
#pragma unroll
      for (int n = 0; n < 2; ++n) bn[n] = ld8(w1 + (32 * wid + 16 * n + l15) * 256 + ko);
#pragma unroll
      for (int m = 0; m < 4; ++m)
#pragma unroll
        for (int n = 0; n < 2; ++n) acc[m][n] = MFMA16(am[m], bn[n], acc[m][n]);
    }
#pragma unroll
    for (int m = 0; m < 4; ++m)
#pragma unroll
      for (int n = 0; n < 2; ++n) {
        int hh = 32 * wid + 16 * n + l15;
        float bb = b1[hh];
#pragma unroll
        for (int r = 0; r < 4; ++r) {
          float v = acc[m][n][r] + bb;
          float sp = (v > 15.f) ? v : __logf(1.f + __expf(v));
          float e2 = __expf(-2.f * sp);
          float th = (1.f - e2) / (1.f + e2);
          hdnS[16 * m + 4 * g + r][hh] = f2bf(v * th);
        }
      }
  }
  __syncthreads();

  // stage 2: out = hdn @ W2^T + b2 + x; wave strip = 32 o-channels
  {
    f32x4 acc[2][4];
#pragma unroll
    for (int m = 0; m < 2; ++m)
#pragma unroll
      for (int n = 0; n < 4; ++n) acc[m][n] = fz4();
    for (int kk = 0; kk < 8; ++kk) {
      int ko = kk * 32 + 8 * g;
      bf16x8 am[2], bn[4];
#pragma unroll
      for (int m = 0; m < 2; ++m) am[m] = ld8(w2 + (32 * wid + 16 * m + l15) * 256 + ko);
#pragma unroll
      for (int n = 0; n < 4; ++n) bn[n] = ld8(&hdnS[16 * n + l15][ko]);
#pragma unroll
      for (int m = 0; m < 2; ++m)
#pragma unroll
        for (int n = 0; n < 4; ++n) acc[m][n] = MFMA16(am[m], bn[n], acc[m][n]);
    }
#pragma unroll
    for (int m = 0; m < 2; ++m)
#pragma unroll
      for (int r = 0; r < 4; ++r) {
        int o = 32 * wid + 16 * m + 4 * g + r;
        float bias = b2[o];
#pragma unroll
        for (int n = 0; n < 4; ++n) {
          int pos = n0 + 16 * n + l15;
          size_t idx = ((size_t)b * 256 + o) * 4096 + pos;
          out[idx] = acc[m][n][r] + bias + x[idx];
        }
      }
  }
}

// ---- workspace layout (bytes) ---------------------------------------------
#define WS_XT 0u          //  8,388,608  xT  [4][4096][256] bf16
#define WS_QT 8388608u    //  2,097,152  Qt  [4][4096][64]  bf16
#define WS_KT 10485760u   //  2,097,152  Kt  [4][4096][64]  bf16
#define WS_VC 12582912u   //  8,388,608  Vc  [4][256][4096] bf16
#define WS_ATT 20971520u  //  8,388,608  attT[4][4096][256] bf16
#define WS_RS 29360128u   //     65,536  rs  [4][4096]      fp32
#define WS_WQ 29425664u   //     32,768
#define WS_WK 29458432u   //     32,768
#define WS_WV 29491200u   //    131,072
#define WS_W1 29622272u   //    131,072
#define WS_W2 29753344u   //    131,072   (end: 29,884,416)

extern "C" void kernel_launch(void* const* d_in, const int* in_sizes, int n_in,
                              void* d_out, int out_size, void* d_ws, size_t ws_size,
                              hipStream_t stream) {
  (void)in_sizes; (void)n_in; (void)out_size; (void)ws_size;
  const float* x  = (const float*)d_in[0];
  const float* WQ = (const float*)d_in[1];
  const float* bQ = (const float*)d_in[2];
  const float* WK = (const float*)d_in[3];
  const float* bK = (const float*)d_in[4];
  const float* WV = (const float*)d_in[5];
  const float* bV = (const float*)d_in[6];
  const float* PE = (const float*)d_in[7];
  const float* W1 = (const float*)d_in[8];
  const float* b1 = (const float*)d_in[9];
  const float* W2 = (const float*)d_in[10];
  const float* b2 = (const float*)d_in[11];
  float* out = (float*)d_out;
  char* ws = (char*)d_ws;

  u16* xT   = (u16*)(ws + WS_XT);
  u16* Qt   = (u16*)(ws + WS_QT);
  u16* Kt   = (u16*)(ws + WS_KT);
  u16* Vc   = (u16*)(ws + WS_VC);
  u16* attT = (u16*)(ws + WS_ATT);
  float* rs = (float*)(ws + WS_RS);
  u16* wqB  = (u16*)(ws + WS_WQ);
  u16* wkB  = (u16*)(ws + WS_WK);
  u16* wvB  = (u16*)(ws + WS_WV);
  u16* w1B  = (u16*)(ws + WS_W1);
  u16* w2B  = (u16*)(ws + WS_W2);

  k_convert<<<896, 256, 0, stream>>>(WQ, WK, WV, W1, W2, wqB, wkB, wvB, w1B, w2B);
  k_transpose<<<dim3(64, 4, 4), 256, 0, stream>>>(x, xT);
  k_proj<<<dim3(128, 4), 256, 0, stream>>>(xT, wqB, wkB, wvB, bQ, bK, bV, PE, Qt, Kt, Vc);
  k_colsum<<<dim3(64, 4), 512, 0, stream>>>(Qt, Kt, rs);
  k_attn<<<dim3(64, 4), 1024, 0, stream>>>(Qt, Kt, Vc, rs, attT);
  k_mlp<<<dim3(64, 4), 512, 0, stream>>>(attT, w1B, b1, w2B, b2, x, out);
}

// Round 13
// 285.244 us; speedup vs baseline: 1.2422x; 1.0025x over previous
//
#include <hip/hip_runtime.h>

// ---------------------------------------------------------------------------
// AttentionHead: B=4, C=256, N=4096, QK=64. Column-softmax attention.
// R12 + XCD batch-pinning: all compute grids linearized with b = id&3 so
// each XCD's L2 holds exactly one batch's tensors (attn working set 3 MB
// < 4 MB L2; R12's dim3 grids mixed all 4 b per XCD -> 10 MB -> 42 MB HBM
// refetch, measured). Kernel bodies identical to R12.
// Workspace: 29,884,416 bytes.
// ---------------------------------------------------------------------------

typedef unsigned short u16;
typedef __attribute__((ext_vector_type(8))) unsigned short ushort8;
typedef __attribute__((ext_vector_type(8))) __bf16 bf16x8;
typedef __attribute__((ext_vector_type(4))) float f32x4;

#define MFMA16(a, b, c) __builtin_amdgcn_mfma_f32_16x16x32_bf16((a), (b), (c), 0, 0, 0)

__device__ __forceinline__ u16 f2bf(float f) {
  unsigned int u = __builtin_bit_cast(unsigned int, f);
  u += 0x7FFFu + ((u >> 16) & 1u);  // round-to-nearest-even
  return (u16)(u >> 16);
}

__device__ __forceinline__ bf16x8 ld8(const u16* p) {
  return __builtin_bit_cast(bf16x8, *reinterpret_cast<const ushort8*>(p));
}

__device__ __forceinline__ f32x4 fz4() {
  f32x4 z = {0.f, 0.f, 0.f, 0.f};
  return z;
}

// ---- convert all weight matrices fp32 -> bf16 (one launch) ----------------
__global__ __launch_bounds__(256) void k_convert(
    const float* __restrict__ wq, const float* __restrict__ wk,
    const float* __restrict__ wv, const float* __restrict__ w1,
    const float* __restrict__ w2, u16* __restrict__ dq, u16* __restrict__ dk,
    u16* __restrict__ dv, u16* __restrict__ d1, u16* __restrict__ d2) {
  int i = blockIdx.x * 256 + threadIdx.x;
  if (i < 16384)       dq[i]           = f2bf(wq[i]);
  else if (i < 32768)  dk[i - 16384]   = f2bf(wk[i - 16384]);
  else if (i < 98304)  dv[i - 32768]   = f2bf(wv[i - 32768]);
  else if (i < 163840) d1[i - 98304]   = f2bf(w1[i - 98304]);
  else                 d2[i - 163840]  = f2bf(w2[i - 163840]);
}

// ---- x [b][256][4096] fp32 -> xT [b][4096][256] bf16 (LDS-tiled) ----------
__global__ __launch_bounds__(256) void k_transpose(const float* __restrict__ x,
                                                   u16* __restrict__ xT) {
  __shared__ float t[64][65];
  int n0 = blockIdx.x * 64, c0 = blockIdx.y * 64, b = blockIdx.z;
  int tx = threadIdx.x & 63, ty = threadIdx.x >> 6;
  const float* xb = x + ((size_t)b * 256 + c0) * 4096 + n0;
#pragma unroll
  for (int i = 0; i < 64; i += 4) t[ty + i][tx] = xb[(size_t)(ty + i) * 4096 + tx];
  __syncthreads();
  u16* xo = xT + ((size_t)b * 4096 + n0) * 256 + c0;
#pragma unroll
  for (int i = 0; i < 64; i += 4) xo[(size_t)(ty + i) * 256 + tx] = f2bf(t[tx][ty + i]);
}

// ---- fused QKV projection: 32-pos tiles, grid 512 linear (b = id&3) -------
__global__ __launch_bounds__(256) void k_proj(
    const u16* __restrict__ xT, const u16* __restrict__ wq,
    const u16* __restrict__ wk, const u16* __restrict__ wv,
    const float* __restrict__ bQ, const float* __restrict__ bK,
    const float* __restrict__ bV, const float* __restrict__ PE,
    u16* __restrict__ Qt, u16* __restrict__ Kt, u16* __restrict__ Vc) {
  int b = blockIdx.x & 3, n0 = (blockIdx.x >> 2) * 32;
  int lane = threadIdx.x & 63, wid = threadIdx.x >> 6;
  int l15 = lane & 15, g = lane >> 4;
  const u16* xrow = xT + ((size_t)b * 4096 + n0) * 256;

  f32x4 aq[2], ak[2], av[4][2];
#pragma unroll
  for (int m = 0; m < 2; ++m) { aq[m] = fz4(); ak[m] = fz4(); }
#pragma unroll
  for (int m = 0; m < 4; ++m)
#pragma unroll
    for (int n = 0; n < 2; ++n) av[m][n] = fz4();

  for (int kk = 0; kk < 8; ++kk) {
    int ko = kk * 32 + g * 8;
    bf16x8 xa[2];
#pragma unroll
    for (int m = 0; m < 2; ++m) xa[m] = ld8(xrow + (16 * m + l15) * 256 + ko);
    bf16x8 fq = ld8(wq + (16 * wid + l15) * 256 + ko);
    bf16x8 fk = ld8(wk + (16 * wid + l15) * 256 + ko);
#pragma unroll
    for (int m = 0; m < 2; ++m) {
      aq[m] = MFMA16(xa[m], fq, aq[m]);
      ak[m] = MFMA16(xa[m], fk, ak[m]);
    }
    bf16x8 fv[4];
#pragma unroll
    for (int m = 0; m < 4; ++m) fv[m] = ld8(wv + (64 * wid + 16 * m + l15) * 256 + ko);
#pragma unroll
    for (int m = 0; m < 4; ++m)
#pragma unroll
      for (int n = 0; n < 2; ++n) av[m][n] = MFMA16(fv[m], xa[n], av[m][n]);
  }

  int o = 16 * wid + l15;
#pragma unroll
  for (int m = 0; m < 2; ++m)
#pragma unroll
    for (int r = 0; r < 4; ++r) {
      int pos = n0 + 16 * m + 4 * g + r;
      float pe = PE[o * 4096 + pos];
      Qt[((size_t)b * 4096 + pos) * 64 + o] = f2bf(aq[m][r] + bQ[o] + pe);
      Kt[((size_t)b * 4096 + pos) * 64 + o] = f2bf(ak[m][r] + bK[o] + pe);
    }
#pragma unroll
  for (int m = 0; m < 4; ++m) {
    int ov = 64 * wid + 16 * m + 4 * g;
#pragma unroll
    for (int r = 0; r < 4; ++r) {
      float bvv = bV[ov + r];
#pragma unroll
      for (int n = 0; n < 2; ++n) {
        int pos = n0 + 16 * n + l15;
        Vc[((size_t)b * 256 + ov + r) * 4096 + pos] = f2bf(av[m][n][r] + bvv);
      }
    }
  }
}

// ---- pass 1: column sums, 512 thr, grid 256 linear (b = id&3) -------------
__global__ __launch_bounds__(512) void k_colsum(const u16* __restrict__ Qt,
                                                const u16* __restrict__ Kt,
                                                float* __restrict__ rs) {
  __shared__ float ps[8][16];
  int b = blockIdx.x & 3, j0 = (blockIdx.x >> 2) * 64;
  int lane = threadIdx.x & 63, wid = threadIdx.x >> 6;  // wid in [0,8)
  int l15 = lane & 15, g = lane >> 4;
  int w4 = wid & 3, ihalf = wid >> 2;
  const u16* qb = Qt + (size_t)b * 262144;
  const u16* kb = Kt + (size_t)b * 262144;
  int j = j0 + 16 * w4 + l15;
  bf16x8 fk[2];
#pragma unroll
  for (int h = 0; h < 2; ++h) fk[h] = ld8(kb + j * 64 + h * 32 + 8 * g);
  float part = 0.f;
  for (int i0 = ihalf * 2048; i0 < ihalf * 2048 + 2048; i0 += 64) {
    f32x4 acc[4];
#pragma unroll
    for (int m = 0; m < 4; ++m) acc[m] = fz4();
#pragma unroll
    for (int m = 0; m < 4; ++m) {
      const u16* qr = qb + (i0 + 16 * m + l15) * 64;
      acc[m] = MFMA16(ld8(qr + 8 * g), fk[0], acc[m]);
      acc[m] = MFMA16(ld8(qr + 32 + 8 * g), fk[1], acc[m]);
    }
#pragma unroll
    for (int m = 0; m < 4; ++m)
#pragma unroll
      for (int r = 0; r < 4; ++r) part += __expf(acc[m][r] * 0.125f);
  }
  part += __shfl_xor(part, 16);
  part += __shfl_xor(part, 32);
  if (g == 0) ps[wid][l15] = part;
  __syncthreads();
  if (ihalf == 0 && g == 0)
    rs[b * 4096 + j] = 1.0f / (ps[w4][l15] + ps[w4 + 4][l15]);
}

// ---- pass 2: attention, 1024 thr, grid 256 linear (b = id&3, XCD-pin) -----
// 256-j steps. Wave w: S+exp for j-strip 16w; PV over channel strip 16w.
__global__ __launch_bounds__(1024) void k_attn(
    const u16* __restrict__ Qt, const u16* __restrict__ Kt,
    const u16* __restrict__ Vc, const float* __restrict__ rs,
    u16* __restrict__ attT) {
  __shared__ u16 P[64][264];  // 256 j + pad (row 528 B, 33x16B)
  int b = blockIdx.x & 3, i0 = (blockIdx.x >> 2) * 64;
  int lane = threadIdx.x & 63, wid = threadIdx.x >> 6;  // wid in [0,16)
  int l15 = lane & 15, g = lane >> 4;
  const u16* qb = Qt + (size_t)b * 262144;
  const u16* kb = Kt + (size_t)b * 262144;
  const u16* vb = Vc + (size_t)b * 1048576;
  const float* rsb = rs + b * 4096;

  bf16x8 aq[4][2];  // block's Q rows (i = i0+16m+l15), held for all j
#pragma unroll
  for (int m = 0; m < 4; ++m)
#pragma unroll
    for (int h = 0; h < 2; ++h)
      aq[m][h] = ld8(qb + (i0 + 16 * m + l15) * 64 + h * 32 + 8 * g);

  f32x4 oacc[4];  // lane: i = i0+16m+4g+r, c = 16*wid+l15
#pragma unroll
  for (int m = 0; m < 4; ++m) oacc[m] = fz4();

  for (int j0 = 0; j0 < 4096; j0 += 256) {
    // S + exp for this wave's 16-j strip (j = j0 + 16*wid + l15)
    const u16* kr = kb + (size_t)(j0 + 16 * wid + l15) * 64;
    bf16x8 fk0 = ld8(kr + 8 * g);
    bf16x8 fk1 = ld8(kr + 32 + 8 * g);
    float rsc = rsb[j0 + 16 * wid + l15];
    f32x4 s[4];
#pragma unroll
    for (int m = 0; m < 4; ++m) {
      s[m] = fz4();
      s[m] = MFMA16(aq[m][0], fk0, s[m]);
      s[m] = MFMA16(aq[m][1], fk1, s[m]);
    }
#pragma unroll
    for (int m = 0; m < 4; ++m)
#pragma unroll
      for (int r = 0; r < 4; ++r)
        P[16 * m + 4 * g + r][16 * wid + l15] = f2bf(__expf(s[m][r] * 0.125f) * rsc);
    __syncthreads();
    // PV: A = P rows i (8 k-chunks of 32 j), B = V rows c (strip 16*wid)
#pragma unroll
    for (int h = 0; h < 8; ++h) {
      bf16x8 ap[4];
#pragma unroll
      for (int m = 0; m < 4; ++m) ap[m] = ld8(&P[16 * m + l15][h * 32 + 8 * g]);
      bf16x8 fv = ld8(vb + (size_t)(16 * wid + l15) * 4096 + j0 + h * 32 + 8 * g);
#pragma unroll
      for (int m = 0; m < 4; ++m) oacc[m] = MFMA16(ap[m], fv, oacc[m]);
    }
    __syncthreads();
  }
  int c = 16 * wid + l15;
#pragma unroll
  for (int m = 0; m < 4; ++m)
#pragma unroll
    for (int r = 0; r < 4; ++r) {
      int pos = i0 + 16 * m + 4 * g + r;
      attT[((size_t)b * 4096 + pos) * 256 + c] = f2bf(oacc[m][r]);
    }
}

// ---- fused MLP, 512 thr, grid 256 linear (b = id&3) -----------------------
__global__ __launch_bounds__(512) void k_mlp(
    const u16* __restrict__ attT, const u16* __restrict__ w1,
    const float* __restrict__ b1, const u16* __restrict__ w2,
    const float* __restrict__ b2, const float* __restrict__ x,
    float* __restrict__ out) {
  __shared__ u16 hdnS[64][264];
  int b = blockIdx.x & 3, n0 = (blockIdx.x >> 2) * 64;
  int lane = threadIdx.x & 63, wid = threadIdx.x >> 6;  // wid in [0,8)
  int l15 = lane & 15, g = lane >> 4;
  const u16* arow = attT + ((size_t)b * 4096 + n0) * 256;

  // stage 1: hdn = mish(att @ W1^T + b1) -> LDS; wave strip = 32 h-channels
  {
    f32x4 acc[4][2];
#pragma unroll
    for (int m = 0; m < 4; ++m)
#pragma unroll
      for (int n = 0; n < 2; ++n) acc[m][n] = fz4();
    for (int kk = 0; kk < 8; ++kk) {
      int ko = kk * 32 + 8 * g;
      bf16x8 am[4], bn[2];
#pragma unroll
      for (int m = 0; m < 4; ++m) am[m] = ld8(arow + (16 * m + l15) * 256 + ko);
#pragma unroll
      for (int n = 0; n < 2; ++n) bn[n] = ld8(w1 + (32 * wid + 16 * n + l15) * 256 + ko);
#pragma unroll
      for (int m = 0; m < 4; ++m)
#pragma unroll
        for (int n = 0; n < 2; ++n) acc[m][n] = MFMA16(am[m], bn[n], acc[m][n]);
    }
#pragma unroll
    for (int m = 0; m < 4; ++m)
#pragma unroll
      for (int n = 0; n < 2; ++n) {
        int hh = 32 * wid + 16 * n + l15;
        float bb = b1[hh];
#pragma unroll
        for (int r = 0; r < 4; ++r) {
          float v = acc[m][n][r] + bb;
          float sp = (v > 15.f) ? v : __logf(1.f + __expf(v));
          float e2 = __expf(-2.f * sp);
          float th = (1.f - e2) / (1.f + e2);
          hdnS[16 * m + 4 * g + r][hh] = f2bf(v * th);
        }
      }
  }
  __syncthreads();

  // stage 2: out = hdn @ W2^T + b2 + x; wave strip = 32 o-channels
  {
    f32x4 acc[2][4];
#pragma unroll
    for (int m = 0; m < 2; ++m)
#pragma unroll
      for (int n = 0; n < 4; ++n) acc[m][n] = fz4();
    for (int kk = 0; kk < 8; ++kk) {
      int ko = kk * 32 + 8 * g;
      bf16x8 am[2], bn[4];
#pragma unroll
      for (int m = 0; m < 2; ++m) am[m] = ld8(w2 + (32 * wid + 16 * m + l15) * 256 + ko);
#pragma unroll
      for (int n = 0; n < 4; ++n) bn[n] = ld8(&hdnS[16 * n + l15][ko]);
#pragma unroll
      for (int m = 0; m < 2; ++m)
#pragma unroll
        for (int n = 0; n < 4; ++n) acc[m][n] = MFMA16(am[m], bn[n], acc[m][n]);
    }
#pragma unroll
    for (int m = 0; m < 2; ++m)
#pragma unroll
      for (int r = 0; r < 4; ++r) {
        int o = 32 * wid + 16 * m + 4 * g + r;
        float bias = b2[o];
#pragma unroll
        for (int n = 0; n < 4; ++n) {
          int pos = n0 + 16 * n + l15;
          size_t idx = ((size_t)b * 256 + o) * 4096 + pos;
          out[idx] = acc[m][n][r] + bias + x[idx];
        }
      }
  }
}

// ---- workspace layout (bytes) ---------------------------------------------
#define WS_XT 0u          //  8,388,608  xT  [4][4096][256] bf16
#define WS_QT 8388608u    //  2,097,152  Qt  [4][4096][64]  bf16
#define WS_KT 10485760u   //  2,097,152  Kt  [4][4096][64]  bf16
#define WS_VC 12582912u   //  8,388,608  Vc  [4][256][4096] bf16
#define WS_ATT 20971520u  //  8,388,608  attT[4][4096][256] bf16
#define WS_RS 29360128u   //     65,536  rs  [4][4096]      fp32
#define WS_WQ 29425664u   //     32,768
#define WS_WK 29458432u   //     32,768
#define WS_WV 29491200u   //    131,072
#define WS_W1 29622272u   //    131,072
#define WS_W2 29753344u   //    131,072   (end: 29,884,416)

extern "C" void kernel_launch(void* const* d_in, const int* in_sizes, int n_in,
                              void* d_out, int out_size, void* d_ws, size_t ws_size,
                              hipStream_t stream) {
  (void)in_sizes; (void)n_in; (void)out_size; (void)ws_size;
  const float* x  = (const float*)d_in[0];
  const float* WQ = (const float*)d_in[1];
  const float* bQ = (const float*)d_in[2];
  const float* WK = (const float*)d_in[3];
  const float* bK = (const float*)d_in[4];
  const float* WV = (const float*)d_in[5];
  const float* bV = (const float*)d_in[6];
  const float* PE = (const float*)d_in[7];
  const float* W1 = (const float*)d_in[8];
  const float* b1 = (const float*)d_in[9];
  const float* W2 = (const float*)d_in[10];
  const float* b2 = (const float*)d_in[11];
  float* out = (float*)d_out;
  char* ws = (char*)d_ws;

  u16* xT   = (u16*)(ws + WS_XT);
  u16* Qt   = (u16*)(ws + WS_QT);
  u16* Kt   = (u16*)(ws + WS_KT);
  u16* Vc   = (u16*)(ws + WS_VC);
  u16* attT = (u16*)(ws + WS_ATT);
  float* rs = (float*)(ws + WS_RS);
  u16* wqB  = (u16*)(ws + WS_WQ);
  u16* wkB  = (u16*)(ws + WS_WK);
  u16* wvB  = (u16*)(ws + WS_WV);
  u16* w1B  = (u16*)(ws + WS_W1);
  u16* w2B  = (u16*)(ws + WS_W2);

  k_convert<<<896, 256, 0, stream>>>(WQ, WK, WV, W1, W2, wqB, wkB, wvB, w1B, w2B);
  k_transpose<<<dim3(64, 4, 4), 256, 0, stream>>>(x, xT);
  k_proj<<<512, 256, 0, stream>>>(xT, wqB, wkB, wvB, bQ, bK, bV, PE, Qt, Kt, Vc);
  k_colsum<<<256, 512, 0, stream>>>(Qt, Kt, rs);
  k_attn<<<256, 1024, 0, stream>>>(Qt, Kt, Vc, rs, attT);
  k_mlp<<<256, 512, 0, stream>>>(attT, w1B, b1, w2B, b2, x, out);
}